// Round 2
// baseline (3924.715 us; speedup 1.0000x reference)
//
#include <hip/hip_runtime.h>

// Problem constants (from reference): T=8, D=512, H=100, C=2, NEG=1
constexpr int D_ = 512;
constexpr int H_ = 100;
constexpr int C_ = 2;
constexpr int T_ = 8;

constexpr int TE = 64;          // edges per block in main kernel
constexpr int DC = 16;          // D-chunk (floats) staged in LDS
constexpr int NC = D_ / DC;     // 32 chunks
constexpr int SB = 128;         // sort segments / blocks
constexpr int STH = 256;        // threads per sort block

// ws layout (ints): [0:8) typeBase | [8:16) typeCount | [16:25) tileBase
//                   [32:32+SB*8) hist/blockBase | [1056 : 1056+E) sorted_e
constexpr int WS_HIST = 32;
constexpr int WS_SORTED = 32 + SB * T_;   // 1056

// ---------------------------------------------------------------------------
// K1: per-segment histogram. SB blocks x STH threads.
// ---------------------------------------------------------------------------
__global__ __launch_bounds__(STH) void k_hist(const int* __restrict__ et, int E, int seg,
                                              int* __restrict__ hist) {
    __shared__ int hb[T_];
    const int b = blockIdx.x, tid = threadIdx.x;
    if (tid < T_) hb[tid] = 0;
    __syncthreads();
    const int segLo = b * seg;
    const int segHi = min(E, segLo + seg);
    const int per = (seg + STH - 1) / STH;
    const int lo = segLo + tid * per;
    const int hi = min(segHi, lo + per);
    int c[T_];
#pragma unroll
    for (int j = 0; j < T_; ++j) c[j] = 0;
    for (int i = lo; i < hi; ++i) {
        int ty = et[i];
#pragma unroll
        for (int j = 0; j < T_; ++j) c[j] += (ty == j) ? 1 : 0;
    }
#pragma unroll
    for (int j = 0; j < T_; ++j)
        if (c[j]) atomicAdd(&hb[j], c[j]);
    __syncthreads();
    if (tid < T_) hist[b * T_ + tid] = hb[tid];
}

// ---------------------------------------------------------------------------
// K2: scan over SB segment histograms (one block of SB threads).
// Produces typeBase/typeCount/tileBase and rewrites hist -> blockBase[b][t].
// ---------------------------------------------------------------------------
__global__ __launch_bounds__(SB) void k_scan(int* __restrict__ hist,
                                             int* __restrict__ typeBase,
                                             int* __restrict__ typeCount,
                                             int* __restrict__ tileBase) {
    __shared__ int sc[SB][T_ + 1];   // stride 9 -> conflict-free
    __shared__ int sbase[T_];
    const int tid = threadIdx.x;
#pragma unroll
    for (int j = 0; j < T_; ++j) sc[tid][j] = hist[tid * T_ + j];
    __syncthreads();
    for (int ofs = 1; ofs < SB; ofs <<= 1) {
        int v[T_];
        if (tid >= ofs) {
#pragma unroll
            for (int j = 0; j < T_; ++j) v[j] = sc[tid - ofs][j];
        }
        __syncthreads();
        if (tid >= ofs) {
#pragma unroll
            for (int j = 0; j < T_; ++j) sc[tid][j] += v[j];
        }
        __syncthreads();
    }
    if (tid == 0) {
        int b = 0, tb = 0;
#pragma unroll
        for (int j = 0; j < T_; ++j) {
            int cntj = sc[SB - 1][j];
            sbase[j] = b;
            typeBase[j] = b;
            typeCount[j] = cntj;
            tileBase[j] = tb;
            b += cntj;
            tb += (cntj + TE - 1) / TE;
        }
        tileBase[T_] = tb;
    }
    __syncthreads();
#pragma unroll
    for (int j = 0; j < T_; ++j)
        hist[tid * T_ + j] = sbase[j] + (tid ? sc[tid - 1][j] : 0);
}

// ---------------------------------------------------------------------------
// K3: stable scatter. SB blocks x STH threads, same segmentation as K1.
// ---------------------------------------------------------------------------
__global__ __launch_bounds__(STH) void k_scatter(const int* __restrict__ et, int E, int seg,
                                                 const int* __restrict__ blockBase,
                                                 int* __restrict__ sorted_e) {
    __shared__ int sc[STH][T_ + 1];
    const int b = blockIdx.x, tid = threadIdx.x;
    const int segLo = b * seg;
    const int segHi = min(E, segLo + seg);
    const int per = (seg + STH - 1) / STH;
    const int lo = segLo + tid * per;
    const int hi = min(segHi, lo + per);
    int c[T_];
#pragma unroll
    for (int j = 0; j < T_; ++j) c[j] = 0;
    for (int i = lo; i < hi; ++i) {
        int ty = et[i];
#pragma unroll
        for (int j = 0; j < T_; ++j) c[j] += (ty == j) ? 1 : 0;
    }
#pragma unroll
    for (int j = 0; j < T_; ++j) sc[tid][j] = c[j];
    __syncthreads();
    for (int ofs = 1; ofs < STH; ofs <<= 1) {
        int v[T_];
        if (tid >= ofs) {
#pragma unroll
            for (int j = 0; j < T_; ++j) v[j] = sc[tid - ofs][j];
        }
        __syncthreads();
        if (tid >= ofs) {
#pragma unroll
            for (int j = 0; j < T_; ++j) sc[tid][j] += v[j];
        }
        __syncthreads();
    }
    int p[T_];
#pragma unroll
    for (int j = 0; j < T_; ++j)
        p[j] = blockBase[b * T_ + j] + (tid ? sc[tid - 1][j] : 0);
    for (int i = lo; i < hi; ++i) {
        int ty = et[i];
        int r = 0;
#pragma unroll
        for (int j = 0; j < T_; ++j) {
            if (ty == j) { r = p[j]; p[j] = r + 1; }
        }
        sorted_e[r] = i;
    }
}

// ---------------------------------------------------------------------------
// Main fused kernel. 24.8 KB LDS (DC=16 double-buffer, no edge union) so
// multiple blocks fit per CU; out-layer done in registers via 16-lane
// butterfly reduce. Async global_load_lds staging with source-side XOR
// swizzle; fused h_save via linear LDS readback.
// ---------------------------------------------------------------------------
__global__ __launch_bounds__(256, 3) void k_main(
    const float* __restrict__ h,
    const float* __restrict__ srcW, const float* __restrict__ srcB,
    const float* __restrict__ dstW, const float* __restrict__ dstB,
    const float* __restrict__ outW, const float* __restrict__ outB,
    const int* __restrict__ sorted_e,
    const int* __restrict__ typeBase, const int* __restrict__ typeCount,
    const int* __restrict__ tileBase,
    float* __restrict__ out, int E)
{
    const int b = blockIdx.x;
    if (b >= tileBase[T_]) return;
    int t = 0;
#pragma unroll
    for (int j = 1; j < T_; ++j) t += (b >= tileBase[j]) ? 1 : 0;
    const int i0   = (b - tileBase[t]) * TE;
    const int cnt  = typeCount[t];
    const int base = typeBase[t];
    const int tid = threadIdx.x;
    const int tx  = tid & 15;
    const int ty  = tid >> 4;

    // stage: [buf][m*256 + r*4 + s4] float4; row r holds global f4-col s4^swz(r)
    __shared__ __align__(16) float4 stg[2][3 * TE * (DC / 4)];   // 24576 B
    __shared__ int eIdx[TE];

    if (tid < TE) {
        int p = i0 + tid;
        eIdx[tid] = sorted_e[base + (p < cnt ? p : i0)];  // clamp pads to valid edge
    }
    __syncthreads();

    const int r   = tid >> 2;                 // staged row (edge slot) 0..63
    const int s4  = tid & 3;                  // f4 slot within row
    const int c4  = s4 ^ ((r >> 2) & 3);      // swizzled global f4-column
    const bool g  = (i0 + r) < cnt;
    const float* gsrc[3];
#pragma unroll
    for (int m = 0; m < 3; ++m)
        gsrc[m] = h + ((size_t)m * E + eIdx[r]) * D_ + (c4 << 2);

    float* const outH = out + (size_t)4 * E;        // h_save region
    const ptrdiff_t hsOfs = outH - h;               // uniform offset h -> h_save

    float4* const st0 = &stg[0][0];
    float4* const st1 = &stg[1][0];

    auto stage_issue = [&](float4* dstF4, int d0c) {
#pragma unroll
        for (int m = 0; m < 3; ++m) {
            __builtin_amdgcn_global_load_lds(
                (const __attribute__((address_space(1))) void*)(gsrc[m] + d0c),
                (__attribute__((address_space(3))) void*)(dstF4 + m * 256 + tid),
                16, 0, 0);
        }
    };

    float accS[4][7], accP[4][7], accN[4][7];
#pragma unroll
    for (int kk = 0; kk < 4; ++kk)
#pragma unroll
        for (int jj = 0; jj < 7; ++jj) { accS[kk][jj] = 0.f; accP[kk][jj] = 0.f; accN[kk][jj] = 0.f; }

    int jcs[7];
#pragma unroll
    for (int jj = 0; jj < 7; ++jj) {
        int j = jj * 16 + tx;
        jcs[jj] = (j < H_) ? j : (H_ - 1);   // clamp; clamped result zeroed later
    }

    int row4[4];
#pragma unroll
    for (int kk = 0; kk < 4; ++kk) row4[kk] = (ty * 4 + kk) * 4;
    const int swy = ty & 3;                  // read-side XOR (== swz of own rows)

    const float* wsBase = srcW + (size_t)t * D_ * H_;
    const float* wdBase = dstW + (size_t)t * D_ * H_;

    stage_issue(st0, 0);   // prologue: chunk 0

#pragma unroll 1
    for (int ch = 0; ch < NC; ++ch) {
        const int d0 = ch * DC;
        float4* const cs = (ch & 1) ? st1 : st0;
        float4* const ns = (ch & 1) ? st0 : st1;

        __syncthreads();   // chunk-ch staging complete (issued one chunk ago)

        if (ch + 1 < NC) stage_issue(ns, d0 + DC);

        // fused h_save: read own linear slots (conflict-free), mirror-store
#pragma unroll
        for (int m = 0; m < 2; ++m) {
            float4 v = cs[m * 256 + tid];
            if (g) *(float4*)(const_cast<float*>(gsrc[m]) + hsOfs + d0) = v;
        }

        const float* pws = wsBase + (size_t)d0 * H_;
        const float* pwd = wdBase + (size_t)d0 * H_;
        float2 Av[3][4];
#pragma unroll
        for (int s_ = 0; s_ < DC; ++s_) {
            const int dd4 = s_ >> 2;
            if ((s_ & 1) == 0) {
                // refresh A fragments: ds_read_b64, 4 distinct bank-quads per inst
#pragma unroll
                for (int m = 0; m < 3; ++m)
#pragma unroll
                    for (int kk = 0; kk < 4; ++kk)
                        Av[m][kk] = *(const float2*)(
                            (const float*)&cs[m * 256 + row4[kk] + (dd4 ^ swy)] + (s_ & 2));
            }
            float wsv[7], wdv[7];
#pragma unroll
            for (int jj = 0; jj < 7; ++jj) {
                wsv[jj] = pws[s_ * H_ + jcs[jj]];
                wdv[jj] = pwd[s_ * H_ + jcs[jj]];
            }
#pragma unroll
            for (int kk = 0; kk < 4; ++kk) {
                float as = (s_ & 1) ? Av[0][kk].y : Av[0][kk].x;
                float ap = (s_ & 1) ? Av[1][kk].y : Av[1][kk].x;
                float an = (s_ & 1) ? Av[2][kk].y : Av[2][kk].x;
#pragma unroll
                for (int jj = 0; jj < 7; ++jj) {
                    accS[kk][jj] = fmaf(as, wsv[jj], accS[kk][jj]);
                    accP[kk][jj] = fmaf(ap, wdv[jj], accP[kk][jj]);
                    accN[kk][jj] = fmaf(an, wdv[jj], accN[kk][jj]);
                }
            }
        }
    }

    // ---- epilogue: bias + relu + out-layer, all in registers ----
    float sb[7], db[7], woA[7], woB[7];
#pragma unroll
    for (int jj = 0; jj < 7; ++jj) {
        sb[jj] = srcB[t * H_ + jcs[jj]];
        db[jj] = dstB[t * H_ + jcs[jj]];
        float2 wo = *(const float2*)(outW + (size_t)t * H_ * C_ + jcs[jj] * C_);
        woA[jj] = wo.x; woB[jj] = wo.y;
    }

    float part[16];   // part[kk*4 + pn*2 + c]
#pragma unroll
    for (int i = 0; i < 16; ++i) part[i] = 0.f;
#pragma unroll
    for (int kk = 0; kk < 4; ++kk) {
#pragma unroll
        for (int jj = 0; jj < 7; ++jj) {
            float s_ = accS[kk][jj] + sb[jj];
            float pe = fmaxf(s_ + accP[kk][jj] + db[jj], 0.f);
            float ne = fmaxf(s_ + accN[kk][jj] + db[jj], 0.f);
            if (jj == 6) {                    // zero clamped duplicate columns
                bool valid = (tx < 4);
                pe = valid ? pe : 0.f;
                ne = valid ? ne : 0.f;
            }
            part[kk * 4 + 0] = fmaf(pe, woA[jj], part[kk * 4 + 0]);
            part[kk * 4 + 1] = fmaf(pe, woB[jj], part[kk * 4 + 1]);
            part[kk * 4 + 2] = fmaf(ne, woA[jj], part[kk * 4 + 2]);
            part[kk * 4 + 3] = fmaf(ne, woB[jj], part[kk * 4 + 3]);
        }
    }

    // 16-lane butterfly exchange-reduce: lane tx ends with total for output tx
    float v8[8];
#pragma unroll
    for (int a = 0; a < 8; ++a) {
        float keep = (tx & 1) ? part[2 * a + 1] : part[2 * a];
        float send = (tx & 1) ? part[2 * a] : part[2 * a + 1];
        v8[a] = keep + __shfl_xor(send, 1);
    }
    float v4[4];
#pragma unroll
    for (int a = 0; a < 4; ++a) {
        float keep = (tx & 2) ? v8[2 * a + 1] : v8[2 * a];
        float send = (tx & 2) ? v8[2 * a] : v8[2 * a + 1];
        v4[a] = keep + __shfl_xor(send, 2);
    }
    float v2_[2];
#pragma unroll
    for (int a = 0; a < 2; ++a) {
        float keep = (tx & 4) ? v4[2 * a + 1] : v4[2 * a];
        float send = (tx & 4) ? v4[2 * a] : v4[2 * a + 1];
        v2_[a] = keep + __shfl_xor(send, 4);
    }
    {
        float keep = (tx & 8) ? v2_[1] : v2_[0];
        float send = (tx & 8) ? v2_[0] : v2_[1];
        float tot = keep + __shfl_xor(send, 8);

        const int kkO = tx >> 2;
        const int pn  = (tx >> 1) & 1;
        const int c   = tx & 1;
        const int k   = ty * 4 + kkO;
        if (i0 + k < cnt) {
            float val = tot + outB[t * C_ + c];
            size_t pidx = (size_t)(base + i0 + k) * C_ + c;
            out[(pn ? (size_t)C_ * E : (size_t)0) + pidx] = val;
        }
    }
}

// ---------------------------------------------------------------------------
extern "C" void kernel_launch(void* const* d_in, const int* in_sizes, int n_in,
                              void* d_out, int out_size, void* d_ws, size_t ws_size,
                              hipStream_t stream) {
    (void)n_in; (void)out_size; (void)ws_size;
    const float* h    = (const float*)d_in[0];
    const float* srcW = (const float*)d_in[1];
    const float* srcB = (const float*)d_in[2];
    const float* dstW = (const float*)d_in[3];
    const float* dstB = (const float*)d_in[4];
    const float* outW = (const float*)d_in[5];
    const float* outB = (const float*)d_in[6];
    const int*   et   = (const int*)d_in[7];
    const int E = in_sizes[7];

    float* out = (float*)d_out;
    int* ws = (int*)d_ws;
    int* typeBase  = ws;
    int* typeCount = ws + 8;
    int* tileBase  = ws + 16;
    int* hist      = ws + WS_HIST;
    int* sorted_e  = ws + WS_SORTED;

    const int seg = (E + SB - 1) / SB;
    k_hist<<<SB, STH, 0, stream>>>(et, E, seg, hist);
    k_scan<<<1, SB, 0, stream>>>(hist, typeBase, typeCount, tileBase);
    k_scatter<<<SB, STH, 0, stream>>>(et, E, seg, hist, sorted_e);

    const int maxTiles = (E + TE - 1) / TE + T_;   // >= sum of per-type ceil tiles
    k_main<<<maxTiles, 256, 0, stream>>>(h, srcW, srcB, dstW, dstB, outW, outB,
                                         sorted_e, typeBase, typeCount, tileBase,
                                         out, E);
}

// Round 3
// 2811.684 us; speedup vs baseline: 1.3959x; 1.3959x over previous
//
#include <hip/hip_runtime.h>

// Problem constants (from reference): T=8, D=512, H=100, C=2, NEG=1
constexpr int D_ = 512;
constexpr int H_ = 100;
constexpr int C_ = 2;
constexpr int T_ = 8;

constexpr int TE = 32;          // edges per block in main kernel
constexpr int DC = 32;          // D-chunk (floats) staged in LDS = one 128B line/row
constexpr int NC = D_ / DC;     // 16 chunks
constexpr int SB = 128;         // sort segments / blocks
constexpr int STH = 256;        // threads per sort block

// ws layout (ints): [0:8) typeBase | [8:16) typeCount | [16:25) tileBase
//                   [32:32+SB*8) hist/blockBase | [1056 : 1056+E) sorted_e
constexpr int WS_HIST = 32;
constexpr int WS_SORTED = 32 + SB * T_;   // 1056

// ---------------------------------------------------------------------------
// K1: per-segment histogram. SB blocks x STH threads.
// ---------------------------------------------------------------------------
__global__ __launch_bounds__(STH) void k_hist(const int* __restrict__ et, int E, int seg,
                                              int* __restrict__ hist) {
    __shared__ int hb[T_];
    const int b = blockIdx.x, tid = threadIdx.x;
    if (tid < T_) hb[tid] = 0;
    __syncthreads();
    const int segLo = b * seg;
    const int segHi = min(E, segLo + seg);
    const int per = (seg + STH - 1) / STH;
    const int lo = segLo + tid * per;
    const int hi = min(segHi, lo + per);
    int c[T_];
#pragma unroll
    for (int j = 0; j < T_; ++j) c[j] = 0;
    for (int i = lo; i < hi; ++i) {
        int ty = et[i];
#pragma unroll
        for (int j = 0; j < T_; ++j) c[j] += (ty == j) ? 1 : 0;
    }
#pragma unroll
    for (int j = 0; j < T_; ++j)
        if (c[j]) atomicAdd(&hb[j], c[j]);
    __syncthreads();
    if (tid < T_) hist[b * T_ + tid] = hb[tid];
}

// ---------------------------------------------------------------------------
// K2: scan over SB segment histograms (one block of SB threads).
// Produces typeBase/typeCount/tileBase and rewrites hist -> blockBase[b][t].
// ---------------------------------------------------------------------------
__global__ __launch_bounds__(SB) void k_scan(int* __restrict__ hist,
                                             int* __restrict__ typeBase,
                                             int* __restrict__ typeCount,
                                             int* __restrict__ tileBase) {
    __shared__ int sc[SB][T_ + 1];   // stride 9 -> conflict-free
    __shared__ int sbase[T_];
    const int tid = threadIdx.x;
#pragma unroll
    for (int j = 0; j < T_; ++j) sc[tid][j] = hist[tid * T_ + j];
    __syncthreads();
    for (int ofs = 1; ofs < SB; ofs <<= 1) {
        int v[T_];
        if (tid >= ofs) {
#pragma unroll
            for (int j = 0; j < T_; ++j) v[j] = sc[tid - ofs][j];
        }
        __syncthreads();
        if (tid >= ofs) {
#pragma unroll
            for (int j = 0; j < T_; ++j) sc[tid][j] += v[j];
        }
        __syncthreads();
    }
    if (tid == 0) {
        int b = 0, tb = 0;
#pragma unroll
        for (int j = 0; j < T_; ++j) {
            int cntj = sc[SB - 1][j];
            sbase[j] = b;
            typeBase[j] = b;
            typeCount[j] = cntj;
            tileBase[j] = tb;
            b += cntj;
            tb += (cntj + TE - 1) / TE;
        }
        tileBase[T_] = tb;
    }
    __syncthreads();
#pragma unroll
    for (int j = 0; j < T_; ++j)
        hist[tid * T_ + j] = sbase[j] + (tid ? sc[tid - 1][j] : 0);
}

// ---------------------------------------------------------------------------
// K3: stable scatter. SB blocks x STH threads, same segmentation as K1.
// ---------------------------------------------------------------------------
__global__ __launch_bounds__(STH) void k_scatter(const int* __restrict__ et, int E, int seg,
                                                 const int* __restrict__ blockBase,
                                                 int* __restrict__ sorted_e) {
    __shared__ int sc[STH][T_ + 1];
    const int b = blockIdx.x, tid = threadIdx.x;
    const int segLo = b * seg;
    const int segHi = min(E, segLo + seg);
    const int per = (seg + STH - 1) / STH;
    const int lo = segLo + tid * per;
    const int hi = min(segHi, lo + per);
    int c[T_];
#pragma unroll
    for (int j = 0; j < T_; ++j) c[j] = 0;
    for (int i = lo; i < hi; ++i) {
        int ty = et[i];
#pragma unroll
        for (int j = 0; j < T_; ++j) c[j] += (ty == j) ? 1 : 0;
    }
#pragma unroll
    for (int j = 0; j < T_; ++j) sc[tid][j] = c[j];
    __syncthreads();
    for (int ofs = 1; ofs < STH; ofs <<= 1) {
        int v[T_];
        if (tid >= ofs) {
#pragma unroll
            for (int j = 0; j < T_; ++j) v[j] = sc[tid - ofs][j];
        }
        __syncthreads();
        if (tid >= ofs) {
#pragma unroll
            for (int j = 0; j < T_; ++j) sc[tid][j] += v[j];
        }
        __syncthreads();
    }
    int p[T_];
#pragma unroll
    for (int j = 0; j < T_; ++j)
        p[j] = blockBase[b * T_ + j] + (tid ? sc[tid - 1][j] : 0);
    for (int i = lo; i < hi; ++i) {
        int ty = et[i];
        int r = 0;
#pragma unroll
        for (int j = 0; j < T_; ++j) {
            if (ty == j) { r = p[j]; p[j] = r + 1; }
        }
        sorted_e[r] = i;
    }
}

// ---------------------------------------------------------------------------
// Main fused kernel. TE=32, DC=32: each (row, chunk) is exactly one 128B
// cache line for both staged loads and fused h_save stores (the round-1
// pattern whose measured traffic was exactly logical), while the double
// buffer is only 24.8 KB so ~3 blocks/CU stay resident. Out-layer in
// registers via 16-lane butterfly reduce.
// ---------------------------------------------------------------------------
__global__ __launch_bounds__(256, 3) void k_main(
    const float* __restrict__ h,
    const float* __restrict__ srcW, const float* __restrict__ srcB,
    const float* __restrict__ dstW, const float* __restrict__ dstB,
    const float* __restrict__ outW, const float* __restrict__ outB,
    const int* __restrict__ sorted_e,
    const int* __restrict__ typeBase, const int* __restrict__ typeCount,
    const int* __restrict__ tileBase,
    float* __restrict__ out, int E)
{
    const int b = blockIdx.x;
    if (b >= tileBase[T_]) return;
    int t = 0;
#pragma unroll
    for (int j = 1; j < T_; ++j) t += (b >= tileBase[j]) ? 1 : 0;
    const int i0   = (b - tileBase[t]) * TE;
    const int cnt  = typeCount[t];
    const int base = typeBase[t];
    const int tid = threadIdx.x;
    const int tx  = tid & 15;
    const int ty  = tid >> 4;

    // stage: [buf][m*256 + r*8 + s8] float4; LDS slot s8 of row r holds
    // global f4-column s8 ^ (r&7)  (XOR within the 128B row line).
    __shared__ __align__(16) float4 stg[2][3 * TE * (DC / 4)];   // 24576 B
    __shared__ int eIdx[TE];

    if (tid < TE) {
        int p = i0 + tid;
        eIdx[tid] = sorted_e[base + (p < cnt ? p : i0)];  // clamp pads to valid edge
    }
    __syncthreads();

    const int r   = tid >> 3;                 // staged row (edge slot) 0..31
    const int s8  = tid & 7;                  // f4 slot within row
    const int c4  = s8 ^ (r & 7);             // swizzled global f4-column
    const bool g  = (i0 + r) < cnt;
    const float* gsrc[3];
#pragma unroll
    for (int m = 0; m < 3; ++m)
        gsrc[m] = h + ((size_t)m * E + eIdx[r]) * D_ + (c4 << 2);

    float* const outH = out + (size_t)4 * E;        // h_save region
    const ptrdiff_t hsOfs = outH - h;               // uniform offset h -> h_save

    float4* const st0 = &stg[0][0];
    float4* const st1 = &stg[1][0];

    auto stage_issue = [&](float4* dstF4, int d0c) {
#pragma unroll
        for (int m = 0; m < 3; ++m) {
            __builtin_amdgcn_global_load_lds(
                (const __attribute__((address_space(1))) void*)(gsrc[m] + d0c),
                (__attribute__((address_space(3))) void*)(dstF4 + m * 256 + tid),
                16, 0, 0);
        }
    };

    float accS[2][7], accP[2][7], accN[2][7];
#pragma unroll
    for (int kk = 0; kk < 2; ++kk)
#pragma unroll
        for (int jj = 0; jj < 7; ++jj) { accS[kk][jj] = 0.f; accP[kk][jj] = 0.f; accN[kk][jj] = 0.f; }

    int jcs[7];
#pragma unroll
    for (int jj = 0; jj < 7; ++jj) {
        int j = jj * 16 + tx;
        jcs[jj] = (j < H_) ? j : (H_ - 1);   // clamp; clamped result zeroed later
    }

    int rowB[2], swk[2];
#pragma unroll
    for (int kk = 0; kk < 2; ++kk) {
        int rr = ty * 2 + kk;                // this thread's compute rows
        rowB[kk] = rr * 8;
        swk[kk]  = rr & 7;
    }

    const float* wsBase = srcW + (size_t)t * D_ * H_;
    const float* wdBase = dstW + (size_t)t * D_ * H_;

    stage_issue(st0, 0);   // prologue: chunk 0

#pragma unroll 1
    for (int ch = 0; ch < NC; ++ch) {
        const int d0 = ch * DC;
        float4* const cs = (ch & 1) ? st1 : st0;
        float4* const ns = (ch & 1) ? st0 : st1;

        __syncthreads();   // chunk-ch staging complete (issued one chunk ago)

        if (ch + 1 < NC) stage_issue(ns, d0 + DC);

        // fused h_save: read own linear slots (conflict-free), mirror-store
        // a full 128B line per 8-lane group
#pragma unroll
        for (int m = 0; m < 2; ++m) {
            float4 v = cs[m * 256 + tid];
            if (g) *(float4*)(const_cast<float*>(gsrc[m]) + hsOfs + d0) = v;
        }

        const float* pws = wsBase + (size_t)d0 * H_;
        const float* pwd = wdBase + (size_t)d0 * H_;
#pragma unroll
        for (int dd4 = 0; dd4 < DC / 4; ++dd4) {
            float4 Av[3][2];
#pragma unroll
            for (int m = 0; m < 3; ++m)
#pragma unroll
                for (int kk = 0; kk < 2; ++kk)
                    Av[m][kk] = cs[m * 256 + rowB[kk] + (dd4 ^ swk[kk])];
#pragma unroll
            for (int q = 0; q < 4; ++q) {
                const int d = dd4 * 4 + q;
                float wsv[7], wdv[7];
#pragma unroll
                for (int jj = 0; jj < 7; ++jj) {
                    wsv[jj] = pws[d * H_ + jcs[jj]];
                    wdv[jj] = pwd[d * H_ + jcs[jj]];
                }
#pragma unroll
                for (int kk = 0; kk < 2; ++kk) {
                    float as = ((const float*)&Av[0][kk])[q];
                    float ap = ((const float*)&Av[1][kk])[q];
                    float an = ((const float*)&Av[2][kk])[q];
#pragma unroll
                    for (int jj = 0; jj < 7; ++jj) {
                        accS[kk][jj] = fmaf(as, wsv[jj], accS[kk][jj]);
                        accP[kk][jj] = fmaf(ap, wdv[jj], accP[kk][jj]);
                        accN[kk][jj] = fmaf(an, wdv[jj], accN[kk][jj]);
                    }
                }
            }
        }
    }

    // ---- epilogue: bias + relu + out-layer, all in registers ----
    float sb[7], db[7], woA[7], woB[7];
#pragma unroll
    for (int jj = 0; jj < 7; ++jj) {
        sb[jj] = srcB[t * H_ + jcs[jj]];
        db[jj] = dstB[t * H_ + jcs[jj]];
        float2 wo = *(const float2*)(outW + (size_t)t * H_ * C_ + jcs[jj] * C_);
        woA[jj] = wo.x; woB[jj] = wo.y;
    }

    float part[8];   // part[kk*4 + pn*2 + c]
#pragma unroll
    for (int i = 0; i < 8; ++i) part[i] = 0.f;
#pragma unroll
    for (int kk = 0; kk < 2; ++kk) {
#pragma unroll
        for (int jj = 0; jj < 7; ++jj) {
            float s_ = accS[kk][jj] + sb[jj];
            float pe = fmaxf(s_ + accP[kk][jj] + db[jj], 0.f);
            float ne = fmaxf(s_ + accN[kk][jj] + db[jj], 0.f);
            if (jj == 6) {                    // zero clamped duplicate columns
                bool valid = (tx < 4);
                pe = valid ? pe : 0.f;
                ne = valid ? ne : 0.f;
            }
            part[kk * 4 + 0] = fmaf(pe, woA[jj], part[kk * 4 + 0]);
            part[kk * 4 + 1] = fmaf(pe, woB[jj], part[kk * 4 + 1]);
            part[kk * 4 + 2] = fmaf(ne, woA[jj], part[kk * 4 + 2]);
            part[kk * 4 + 3] = fmaf(ne, woB[jj], part[kk * 4 + 3]);
        }
    }

    // 16-lane butterfly: selector bits (c, pn, kk) from tx; lanes tx and tx+8
    // end duplicated -> guard tx<8.
    float v4[4];
#pragma unroll
    for (int a = 0; a < 4; ++a) {
        float keep = (tx & 1) ? part[2 * a + 1] : part[2 * a];
        float send = (tx & 1) ? part[2 * a] : part[2 * a + 1];
        v4[a] = keep + __shfl_xor(send, 1);
    }
    float v2_[2];
#pragma unroll
    for (int a = 0; a < 2; ++a) {
        float keep = (tx & 2) ? v4[2 * a + 1] : v4[2 * a];
        float send = (tx & 2) ? v4[2 * a] : v4[2 * a + 1];
        v2_[a] = keep + __shfl_xor(send, 2);
    }
    {
        float keep = (tx & 4) ? v2_[1] : v2_[0];
        float send = (tx & 4) ? v2_[0] : v2_[1];
        float v1 = keep + __shfl_xor(send, 4);
        float tot = v1 + __shfl_xor(v1, 8);

        const int c   = tx & 1;
        const int pn  = (tx >> 1) & 1;
        const int kkO = (tx >> 2) & 1;
        const int k   = ty * 2 + kkO;
        if (tx < 8 && (i0 + k) < cnt) {
            float val = tot + outB[t * C_ + c];
            size_t pidx = (size_t)(base + i0 + k) * C_ + c;
            out[(pn ? (size_t)C_ * E : (size_t)0) + pidx] = val;
        }
    }
}

// ---------------------------------------------------------------------------
extern "C" void kernel_launch(void* const* d_in, const int* in_sizes, int n_in,
                              void* d_out, int out_size, void* d_ws, size_t ws_size,
                              hipStream_t stream) {
    (void)n_in; (void)out_size; (void)ws_size;
    const float* h    = (const float*)d_in[0];
    const float* srcW = (const float*)d_in[1];
    const float* srcB = (const float*)d_in[2];
    const float* dstW = (const float*)d_in[3];
    const float* dstB = (const float*)d_in[4];
    const float* outW = (const float*)d_in[5];
    const float* outB = (const float*)d_in[6];
    const int*   et   = (const int*)d_in[7];
    const int E = in_sizes[7];

    float* out = (float*)d_out;
    int* ws = (int*)d_ws;
    int* typeBase  = ws;
    int* typeCount = ws + 8;
    int* tileBase  = ws + 16;
    int* hist      = ws + WS_HIST;
    int* sorted_e  = ws + WS_SORTED;

    const int seg = (E + SB - 1) / SB;
    k_hist<<<SB, STH, 0, stream>>>(et, E, seg, hist);
    k_scan<<<1, SB, 0, stream>>>(hist, typeBase, typeCount, tileBase);
    k_scatter<<<SB, STH, 0, stream>>>(et, E, seg, hist, sorted_e);

    const int maxTiles = (E + TE - 1) / TE + T_;   // >= sum of per-type ceil tiles
    k_main<<<maxTiles, 256, 0, stream>>>(h, srcW, srcB, dstW, dstB, outW, outB,
                                         sorted_e, typeBase, typeCount, tileBase,
                                         out, E);
}